// Round 6
// baseline (1364.063 us; speedup 1.0000x reference)
//
#include <hip/hip_runtime.h>
#include <hip/hip_bf16.h>
#include <math.h>

#define N_  512
#define D_  384
#define H_  12
#define DK_ 32
#define P_  128

typedef short short8 __attribute__((ext_vector_type(8)));
typedef float f32x4  __attribute__((ext_vector_type(4)));

static __device__ __forceinline__ unsigned short f2bf(float f) {
    union { float f; unsigned int u; } v; v.f = f;
    unsigned int r = (v.u + 0x7FFFu + ((v.u >> 16) & 1u)) >> 16;  // RNE
    return (unsigned short)r;
}
static __device__ __forceinline__ float bf2f(unsigned short u) {
    union { unsigned int u; float f; } v; v.u = ((unsigned int)u) << 16;
    return v.f;
}
static __device__ __forceinline__ short2 pk2bf(float a, float b) {
    __hip_bfloat162 h = __float22bfloat162_rn(make_float2(a, b));
    return *(short2*)&h;
}
typedef union { short8 v; short2 h2[4]; } s8u;
typedef union { short2 h2[2]; unsigned long long u; } s4u;

// ---------------------------------------------------------------------------
// K1: projections + affine ONLY (320 blocks x 384 thr; pair GEMM moved to k_big)
// ---------------------------------------------------------------------------
__global__ __launch_bounds__(384) void k_front(
    const float* __restrict__ x1d, const float* __restrict__ pose_t,
    const float* __restrict__ pose_r,
    const float* __restrict__ w_sq, const float* __restrict__ w_sk,
    const float* __restrict__ w_sv, const float* __restrict__ w_pq,
    const float* __restrict__ w_pk, const float* __restrict__ w_pv,
    float* __restrict__ qs, float* __restrict__ kst,
    float* __restrict__ qp, float* __restrict__ kpt,
    unsigned short* __restrict__ vcatT)
{
    __shared__ float raw[8][288];
    __shared__ float Rsh[8][9];
    __shared__ float Tsh[8][3];

    const int t   = threadIdx.x;
    const int b   = blockIdx.x;
    const int seg = b >> 6;            // 0..4
    const int i0  = (b & 63) * 8;

    if (seg < 3) {
        const float* __restrict__ w = (seg == 0) ? w_sq : (seg == 1) ? w_sk : w_sv;
        float acc[8];
        #pragma unroll
        for (int r = 0; r < 8; ++r) acc[r] = 0.f;
        for (int d = 0; d < D_; d += 4) {
            float4 xr[8];
            #pragma unroll
            for (int r = 0; r < 8; ++r)
                xr[r] = *(const float4*)(x1d + (i0 + r) * D_ + d);
            #pragma unroll
            for (int e = 0; e < 4; ++e) {
                float wv = w[(d + e) * D_ + t];
                #pragma unroll
                for (int r = 0; r < 8; ++r)
                    acc[r] += ((const float*)&xr[r])[e] * wv;
            }
        }
        if (seg == 0) {
            #pragma unroll
            for (int r = 0; r < 8; ++r) qs[(i0 + r) * D_ + t] = acc[r];
        } else if (seg == 1) {
            *(float4*)(kst + t * N_ + i0)     = make_float4(acc[0], acc[1], acc[2], acc[3]);
            *(float4*)(kst + t * N_ + i0 + 4) = make_float4(acc[4], acc[5], acc[6], acc[7]);
        } else {
            int h = t >> 5, c = t & 31;
            s8u sv;
            #pragma unroll
            for (int r = 0; r < 4; ++r) sv.h2[r] = pk2bf(acc[2*r], acc[2*r+1]);
            *(short8*)(vcatT + ((size_t)h * 64 + c) * N_ + i0) = sv.v;
        }
    } else {
        if (t < 72) Rsh[t / 9][t % 9] = pose_r[(i0 + t / 9) * 9 + t % 9];
        else if (t < 96) {
            int r = (t - 72) / 3, c = (t - 72) % 3;
            Tsh[r][c] = pose_t[(i0 + r) * 3 + c];
        }

        if (t < 288) {
            const float* __restrict__ w;
            int col, ldw;
            if (seg == 3) {
                if (t < 144) { w = w_pq; col = t;       ldw = 144; }
                else         { w = w_pk; col = t - 144; ldw = 144; }
            } else         { w = w_pv; col = t;       ldw = 288; }
            float acc[8];
            #pragma unroll
            for (int r = 0; r < 8; ++r) acc[r] = 0.f;
            for (int d = 0; d < D_; d += 4) {
                float4 xr[8];
                #pragma unroll
                for (int r = 0; r < 8; ++r)
                    xr[r] = *(const float4*)(x1d + (i0 + r) * D_ + d);
                #pragma unroll
                for (int e = 0; e < 4; ++e) {
                    float wv = w[(d + e) * ldw + col];
                    #pragma unroll
                    for (int r = 0; r < 8; ++r)
                        acc[r] += ((const float*)&xr[r])[e] * wv;
                }
            }
            #pragma unroll
            for (int r = 0; r < 8; ++r) raw[r][t] = acc[r];
        }
        __syncthreads();

        if (t < 288) {
            const int x3   = t % 3;
            const int base = t - x3;
            if (seg == 3) {
                const int c = (t < 144) ? t : t - 144;
                if (t < 144) {
                    #pragma unroll
                    for (int r = 0; r < 8; ++r) {
                        float g = Rsh[r][0 + x3] * raw[r][base]
                                + Rsh[r][3 + x3] * raw[r][base + 1]
                                + Rsh[r][6 + x3] * raw[r][base + 2] + Tsh[r][x3];
                        qp[(i0 + r) * 144 + c] = g;
                    }
                } else {
                    float g[8];
                    #pragma unroll
                    for (int r = 0; r < 8; ++r)
                        g[r] = Rsh[r][0 + x3] * raw[r][base]
                             + Rsh[r][3 + x3] * raw[r][base + 1]
                             + Rsh[r][6 + x3] * raw[r][base + 2] + Tsh[r][x3];
                    *(float4*)(kpt + c * N_ + i0)     = make_float4(g[0], g[1], g[2], g[3]);
                    *(float4*)(kpt + c * N_ + i0 + 4) = make_float4(g[4], g[5], g[6], g[7]);
                }
            } else {
                int h = t / 24, pc = t % 24;
                float g[8];
                #pragma unroll
                for (int r = 0; r < 8; ++r)
                    g[r] = Rsh[r][0 + x3] * raw[r][base]
                         + Rsh[r][3 + x3] * raw[r][base + 1]
                         + Rsh[r][6 + x3] * raw[r][base + 2] + Tsh[r][x3];
                s8u sv;
                #pragma unroll
                for (int r = 0; r < 4; ++r) sv.h2[r] = pk2bf(g[2*r], g[2*r+1]);
                *(short8*)(vcatT + ((size_t)h * 64 + 32 + pc) * N_ + i0) = sv.v;
            }
        }
    }
}

// ---------------------------------------------------------------------------
// K2 (k_big): one block per i (512 blocks x 512 thr). Single pass over x2d:
//   P0: stage x2d[i] (512x128 fp32) -> bf16 XOR-swizzled LDS (128KB)
//   P2: pair logits via MFMA from LDS          -> vbuf fp32 [12][512]
//   P3: + scalar/point/bias logits, softmax    -> attn (global bf16 + LDS)
//   P4: tmp[i] = attn @ x2d  (from LDS bf16)   -> tmp global
// x2d is read ONCE for the whole pipeline; pairlog and k_mid's x2d re-read
// are deleted. LDS total 158528 B -> 1 WG/CU, 8 waves.
// ---------------------------------------------------------------------------
__global__ __launch_bounds__(512) void k_big(
    const float* __restrict__ x2d, const float* __restrict__ w_pb,
    const float* __restrict__ qs, const float* __restrict__ kst,
    const float* __restrict__ qp, const float* __restrict__ kpt,
    const float* __restrict__ bias, const float* __restrict__ tpw,
    unsigned short* __restrict__ attn_bf, float* __restrict__ tmp)
{
    __shared__ unsigned char smem[158528];
    char*  x2b  = (char*)smem;                       // bf16 [512][128], swizzled
    float* vbuf = (float*)(smem + 131072);           // fp32 [12][512] pair logits
    unsigned int* abufw = (unsigned int*)vbuf;       // alias: [512][6] 2xbf16 attn
    float* red  = vbuf + 3072;                       // fp32 [1536] tmp reduce
    float* qsh  = (float*)(smem + 131072 + 24576);   // [384]
    float* qph  = qsh + 384;                         // [144]
    float* wredm = qph + 144;                        // [8][12]
    float* wreds = wredm + 96;                       // [8][12]

    const int i    = blockIdx.x;
    const int t    = threadIdx.x;
    const int lane = t & 63;
    const int wid  = t >> 6;        // 0..7
    const int quad = lane >> 4;
    const int col  = lane & 15;

    // ---- P0: stage q rows + x2d[i] -> swizzled bf16 LDS ----
    if (t < 384) qsh[t] = qs[i * D_ + t];
    if (t < 144) qph[t] = qp[i * 144 + t];
    {
        const float* xb = x2d + (size_t)i * N_ * P_;
        const int jl = t >> 5, p4 = t & 31;
        #pragma unroll 4
        for (int q2 = 0; q2 < 32; ++q2) {
            int j = q2 * 16 + jl;
            float4 f = *(const float4*)(xb + j * P_ + p4 * 4);
            s4u sv; sv.h2[0] = pk2bf(f.x, f.y); sv.h2[1] = pk2bf(f.z, f.w);
            int byte = (j * 256 + p4 * 8) ^ ((j & 7) << 4);
            *(unsigned long long*)(x2b + byte) = sv.u;
        }
    }
    __syncthreads();   // B1

    // ---- P2: pair logits MFMA ----
    {
        const float pair_w = 0.57735027f;
        short8 bfr[4];
        #pragma unroll
        for (int kt = 0; kt < 4; ++kt) {
            #pragma unroll
            for (int jj = 0; jj < 8; ++jj) {
                int p = kt * 32 + quad * 8 + jj;
                bfr[kt][jj] = (col < 12) ? (short)f2bf(w_pb[p * 12 + col]) : (short)0;
            }
        }
        #pragma unroll
        for (int s = 0; s < 4; ++s) {
            const int jt   = wid * 4 + s;
            const int jrow = jt * 16 + col;
            f32x4 acc = {0.f, 0.f, 0.f, 0.f};
            #pragma unroll
            for (int kt = 0; kt < 4; ++kt) {
                int addr = (jrow * 256 + (kt * 32 + quad * 8) * 2) ^ ((jrow & 7) << 4);
                short8 a = *(const short8*)(x2b + addr);
                acc = __builtin_amdgcn_mfma_f32_16x16x32_bf16(a, bfr[kt], acc, 0, 0, 0);
            }
            if (col < 12) {
                #pragma unroll
                for (int r = 0; r < 4; ++r)
                    vbuf[col * N_ + jt * 16 + quad * 4 + r] = pair_w * acc[r];
            }
        }
    }
    __syncthreads();   // B2

    // ---- P3: full logits + softmax (thread j = t) ----
    {
        const int j = t;
        const float scalar_w = 0.10206207f;
        float v[12];
        #pragma unroll
        for (int h = 0; h < 12; ++h) {
            float kv[32];
            #pragma unroll
            for (int c = 0; c < 32; ++c) kv[c] = kst[(h * 32 + c) * N_ + j];
            float kp[12];
            #pragma unroll
            for (int c = 0; c < 12; ++c) kp[c] = kpt[(h * 12 + c) * N_ + j];
            float s = 0.f;
            #pragma unroll
            for (int c = 0; c < 32; ++c) s += qsh[h * 32 + c] * kv[c];
            float dsum = 0.f;
            #pragma unroll
            for (int p = 0; p < 4; ++p) {
                float dx = qph[h * 12 + p * 3 + 0] - kp[p * 3 + 0];
                float dy = qph[h * 12 + p * 3 + 1] - kp[p * 3 + 1];
                float dz = qph[h * 12 + p * 3 + 2] - kp[p * 3 + 2];
                dsum += sqrtf(dx * dx + dy * dy + dz * dz);
            }
            float pwh = 0.13608276f * log1pf(expf(tpw[h]));
            v[h] = scalar_w * s - 0.5f * pwh * dsum
                 + bias[i * N_ + j] + vbuf[h * N_ + j];
        }

        // wave max per h
        #pragma unroll
        for (int h = 0; h < 12; ++h) {
            float mt = v[h];
            #pragma unroll
            for (int off = 1; off < 64; off <<= 1)
                mt = fmaxf(mt, __shfl_xor(mt, off));
            if (lane == 0) wredm[wid * 12 + h] = mt;
        }
        __syncthreads();   // B3 (all vbuf reads done before this)

        float m[12];
        #pragma unroll
        for (int h = 0; h < 12; ++h) {
            float mm = wredm[h];
            #pragma unroll
            for (int w = 1; w < 8; ++w) mm = fmaxf(mm, wredm[w * 12 + h]);
            m[h] = mm;
        }
        float e[12];
        #pragma unroll
        for (int h = 0; h < 12; ++h) {
            e[h] = __expf(v[h] - m[h]);
            float s2 = e[h];
            #pragma unroll
            for (int off = 1; off < 64; off <<= 1)
                s2 += __shfl_xor(s2, off);
            if (lane == 0) wreds[wid * 12 + h] = s2;
        }
        // zero tmp-reduce buffer (safe: vbuf reads completed before B3)
        for (int idx = t; idx < 1536; idx += 512) red[idx] = 0.f;
        __syncthreads();   // B4

        float a[12];
        #pragma unroll
        for (int h = 0; h < 12; ++h) {
            float ss = wreds[h];
            #pragma unroll
            for (int w = 1; w < 8; ++w) ss += wreds[w * 12 + h];
            a[h] = e[h] * (1.0f / ss);
        }
        #pragma unroll
        for (int k = 0; k < 6; ++k) {
            short2 pk = pk2bf(a[2 * k], a[2 * k + 1]);
            abufw[j * 6 + k] = *(unsigned int*)&pk;
        }
        #pragma unroll
        for (int h = 0; h < 12; ++h)
            attn_bf[((size_t)(h * N_ + i)) * N_ + j] = f2bf(a[h]);
    }
    __syncthreads();   // B5

    // ---- P4: tmp[i] = attn @ x2d (from LDS bf16) ----
    {
        const int p2 = (lane) * 2;          // 0..126 even (64 lanes x 2p = 128)
        float acc[12][2];
        #pragma unroll
        for (int h = 0; h < 12; ++h) { acc[h][0] = 0.f; acc[h][1] = 0.f; }
        for (int jj = 0; jj < 64; ++jj) {
            int j = wid * 64 + jj;
            int byte = (j * 256 + p2 * 2) ^ ((j & 7) << 4);
            unsigned int xw = *(const unsigned int*)(x2b + byte);
            float x0 = bf2f((unsigned short)(xw & 0xffff));
            float x1 = bf2f((unsigned short)(xw >> 16));
            #pragma unroll
            for (int k = 0; k < 6; ++k) {
                unsigned int aw = abufw[j * 6 + k];          // broadcast
                float a0 = bf2f((unsigned short)(aw & 0xffff));
                float a1 = bf2f((unsigned short)(aw >> 16));
                acc[2 * k][0]     += a0 * x0; acc[2 * k][1]     += a0 * x1;
                acc[2 * k + 1][0] += a1 * x0; acc[2 * k + 1][1] += a1 * x1;
            }
        }
        #pragma unroll
        for (int h = 0; h < 12; ++h) {
            atomicAdd(&red[h * 128 + p2],     acc[h][0]);
            atomicAdd(&red[h * 128 + p2 + 1], acc[h][1]);
        }
    }
    __syncthreads();   // B6
    for (int idx = t; idx < 1536; idx += 512)
        tmp[(size_t)i * 1536 + idx] = red[idx];
}

// ---------------------------------------------------------------------------
// K3 (k_aggr): attn_bf @ vcatT via MFMA (384 blocks x 256 thr)
// ---------------------------------------------------------------------------
__global__ __launch_bounds__(256) void k_aggr(
    const unsigned short* __restrict__ attn_bf,
    const unsigned short* __restrict__ vcatT,
    float* __restrict__ feat, float* __restrict__ outpg)
{
    const int t    = threadIdx.x;
    const int bid  = blockIdx.x;
    const int h    = bid >> 5;
    const int i0   = (bid & 31) << 4;
    const int wid  = t >> 6;
    const int lane = t & 63;
    const int quad = lane >> 4;
    const int col  = lane & 15;
    const int c    = wid * 16 + col;
    const bool cvalid = (c < 56);

    const unsigned short* arow = attn_bf + ((size_t)(h * N_ + i0 + col)) * N_;
    const unsigned short* brow = vcatT + ((size_t)h * 64 + c) * N_;

    f32x4 acc = {0.f, 0.f, 0.f, 0.f};
    #pragma unroll
    for (int kt = 0; kt < 16; ++kt) {
        const int k0 = kt * 32 + quad * 8;
        short8 a = *(const short8*)(arow + k0);
        short8 b;
        if (cvalid) b = *(const short8*)(brow + k0);
        else { b[0]=0;b[1]=0;b[2]=0;b[3]=0;b[4]=0;b[5]=0;b[6]=0;b[7]=0; }
        acc = __builtin_amdgcn_mfma_f32_16x16x32_bf16(a, b, acc, 0, 0, 0);
    }
    #pragma unroll
    for (int r = 0; r < 4; ++r) {
        int i = i0 + quad * 4 + r;
        if (c < 32)       feat[(size_t)i * 1152 + h * 32 + c] = acc[r];
        else if (c < 56)  outpg[((size_t)i * 12 + h) * 24 + (c - 32)] = acc[r];
    }
}

__global__ __launch_bounds__(384) void k_feat(
    const float* __restrict__ tmp, const float* __restrict__ outpg,
    const float* __restrict__ pose_t, const float* __restrict__ pose_r,
    const float* __restrict__ w_pairv, float* __restrict__ feat)
{
    const int i = blockIdx.x;
    const int t = threadIdx.x;
    __shared__ float tsh[1536];
    __shared__ float pg[288];
    __shared__ float pl[288];
    __shared__ float Rsh[9], Tsh[3];

    for (int idx = t; idx < 1536; idx += 384) tsh[idx] = tmp[(size_t)i * 1536 + idx];
    if (t < 288) pg[t] = outpg[i * 288 + t];
    if (t < 9) Rsh[t] = pose_r[i * 9 + t];
    if (t < 3) Tsh[t] = pose_t[i * 3 + t];
    __syncthreads();

    {
        int h = t >> 5;
        const float* ts = tsh + h * 128;
        float acc = 0.f;
        #pragma unroll 4
        for (int p = 0; p < 128; ++p) acc += ts[p] * w_pairv[p * D_ + t];
        feat[(size_t)i * 1152 + 672 + t] = acc;
    }
    if (t < 288) {
        int x3 = t % 3, base = t - x3;
        float g0 = pg[base + 0] - Tsh[0];
        float g1 = pg[base + 1] - Tsh[1];
        float g2 = pg[base + 2] - Tsh[2];
        float v = Rsh[x3*3+0]*g0 + Rsh[x3*3+1]*g1 + Rsh[x3*3+2]*g2;
        pl[t] = v;
        feat[(size_t)i * 1152 + 384 + t] = v;
    }
    __syncthreads();
    if (t < 96) {
        float a = pl[t*3], b = pl[t*3+1], c = pl[t*3+2];
        feat[(size_t)i * 1152 + 1056 + t] = sqrtf(a*a + b*b + c*c);
    }
}

__global__ __launch_bounds__(384) void k_out_part(
    const float* __restrict__ feat, const float* __restrict__ w_out,
    float* __restrict__ part)
{
    const int kc = blockIdx.x >> 6;
    const int i0 = (blockIdx.x & 63) * 8;
    const int t  = threadIdx.x;
    const int k0 = kc * 144;

    float acc[8];
    #pragma unroll
    for (int r = 0; r < 8; ++r) acc[r] = 0.f;

    for (int d = 0; d < 144; d += 4) {
        float4 fr[8];
        #pragma unroll
        for (int r = 0; r < 8; ++r)
            fr[r] = *(const float4*)(feat + (size_t)(i0 + r) * 1152 + k0 + d);
        #pragma unroll
        for (int e = 0; e < 4; ++e) {
            float wv = w_out[(size_t)(k0 + d + e) * D_ + t];
            #pragma unroll
            for (int r = 0; r < 8; ++r)
                acc[r] += ((const float*)&fr[r])[e] * wv;
        }
    }
    #pragma unroll
    for (int r = 0; r < 8; ++r)
        part[((size_t)kc * N_ + i0 + r) * D_ + t] = acc[r];
}

__global__ __launch_bounds__(256) void k_out_red(
    const float* __restrict__ part, const float* __restrict__ b_out,
    float* __restrict__ out)
{
    const int idx = blockIdx.x * 256 + threadIdx.x;
    float s = b_out[idx % D_];
    #pragma unroll
    for (int kc = 0; kc < 8; ++kc) s += part[(size_t)kc * (N_ * D_) + idx];
    out[idx] = s;
}

extern "C" void kernel_launch(void* const* d_in, const int* in_sizes, int n_in,
                              void* d_out, int out_size, void* d_ws, size_t ws_size,
                              hipStream_t stream)
{
    (void)in_sizes; (void)n_in; (void)out_size; (void)ws_size;
    const float* x1d     = (const float*)d_in[0];
    const float* x2d     = (const float*)d_in[1];
    const float* pose_t  = (const float*)d_in[2];
    const float* pose_r  = (const float*)d_in[3];
    const float* bias    = (const float*)d_in[4];
    const float* w_sq    = (const float*)d_in[5];
    const float* w_sk    = (const float*)d_in[6];
    const float* w_sv    = (const float*)d_in[7];
    const float* w_pb    = (const float*)d_in[8];
    const float* w_pq    = (const float*)d_in[9];
    const float* w_pk    = (const float*)d_in[10];
    const float* w_pv    = (const float*)d_in[11];
    const float* tpw     = (const float*)d_in[12];
    const float* w_pairv = (const float*)d_in[13];
    const float* w_out   = (const float*)d_in[14];
    const float* b_out   = (const float*)d_in[15];
    float* out = (float*)d_out;

    float* ws = (float*)d_ws;
    float* qs      = ws;
    float* kst     = qs      + 196608;
    float* qp      = kst     + 196608;
    float* kpt     = qp      + 73728;
    float* pairlog = kpt     + 73728;    // unused now (kept for layout stability)
    float* tmp     = pairlog + 3145728;
    float* outpg   = tmp     + 786432;
    float* feat    = outpg   + 147456;
    float* part    = feat    + 589824;   // 1572864 floats
    unsigned short* attn_bf = (unsigned short*)(part + 1572864);  // 12*512*512
    unsigned short* vcatT   = attn_bf + (size_t)12 * N_ * N_;     // 12*64*512

    hipLaunchKernelGGL(k_front, dim3(320), dim3(384), 0, stream,
                       x1d, pose_t, pose_r, w_sq, w_sk, w_sv, w_pq, w_pk, w_pv,
                       qs, kst, qp, kpt, vcatT);
    hipLaunchKernelGGL(k_big, dim3(N_), dim3(512), 0, stream,
                       x2d, w_pb, qs, kst, qp, kpt, bias, tpw, attn_bf, tmp);
    hipLaunchKernelGGL(k_aggr, dim3(384), dim3(256), 0, stream,
                       attn_bf, vcatT, feat, outpg);
    hipLaunchKernelGGL(k_feat, dim3(N_), dim3(384), 0, stream,
                       tmp, outpg, pose_t, pose_r, w_pairv, feat);
    hipLaunchKernelGGL(k_out_part, dim3(512), dim3(384), 0, stream,
                       feat, w_out, part);
    hipLaunchKernelGGL(k_out_red, dim3(768), dim3(256), 0, stream,
                       part, b_out, out);
}

// Round 7
// 1157.762 us; speedup vs baseline: 1.1782x; 1.1782x over previous
//
#include <hip/hip_runtime.h>
#include <hip/hip_bf16.h>
#include <math.h>

#define N_  512
#define D_  384
#define H_  12
#define DK_ 32
#define P_  128

typedef short short8 __attribute__((ext_vector_type(8)));
typedef float f32x4  __attribute__((ext_vector_type(4)));

static __device__ __forceinline__ unsigned short f2bf(float f) {
    union { float f; unsigned int u; } v; v.f = f;
    unsigned int r = (v.u + 0x7FFFu + ((v.u >> 16) & 1u)) >> 16;  // RNE
    return (unsigned short)r;
}
static __device__ __forceinline__ float bf2f(unsigned short u) {
    union { unsigned int u; float f; } v; v.u = ((unsigned int)u) << 16;
    return v.f;
}
static __device__ __forceinline__ short2 pk2bf(float a, float b) {
    __hip_bfloat162 h = __float22bfloat162_rn(make_float2(a, b));
    return *(short2*)&h;
}
typedef union { short8 v; short2 h2[4]; } s8u;
typedef union { short2 h2[2]; unsigned long long u; } s4u;

// ---------------------------------------------------------------------------
// K1: projections + affine ONLY (320 blocks x 384 thr)
// ---------------------------------------------------------------------------
__global__ __launch_bounds__(384) void k_front(
    const float* __restrict__ x1d, const float* __restrict__ pose_t,
    const float* __restrict__ pose_r,
    const float* __restrict__ w_sq, const float* __restrict__ w_sk,
    const float* __restrict__ w_sv, const float* __restrict__ w_pq,
    const float* __restrict__ w_pk, const float* __restrict__ w_pv,
    float* __restrict__ qs, float* __restrict__ kst,
    float* __restrict__ qp, float* __restrict__ kpt,
    unsigned short* __restrict__ vcatT)
{
    __shared__ float raw[8][288];
    __shared__ float Rsh[8][9];
    __shared__ float Tsh[8][3];

    const int t   = threadIdx.x;
    const int b   = blockIdx.x;
    const int seg = b >> 6;            // 0..4
    const int i0  = (b & 63) * 8;

    if (seg < 3) {
        const float* __restrict__ w = (seg == 0) ? w_sq : (seg == 1) ? w_sk : w_sv;
        float acc[8];
        #pragma unroll
        for (int r = 0; r < 8; ++r) acc[r] = 0.f;
        for (int d = 0; d < D_; d += 4) {
            float4 xr[8];
            #pragma unroll
            for (int r = 0; r < 8; ++r)
                xr[r] = *(const float4*)(x1d + (i0 + r) * D_ + d);
            #pragma unroll
            for (int e = 0; e < 4; ++e) {
                float wv = w[(d + e) * D_ + t];
                #pragma unroll
                for (int r = 0; r < 8; ++r)
                    acc[r] += ((const float*)&xr[r])[e] * wv;
            }
        }
        if (seg == 0) {
            #pragma unroll
            for (int r = 0; r < 8; ++r) qs[(i0 + r) * D_ + t] = acc[r];
        } else if (seg == 1) {
            *(float4*)(kst + t * N_ + i0)     = make_float4(acc[0], acc[1], acc[2], acc[3]);
            *(float4*)(kst + t * N_ + i0 + 4) = make_float4(acc[4], acc[5], acc[6], acc[7]);
        } else {
            int h = t >> 5, c = t & 31;
            s8u sv;
            #pragma unroll
            for (int r = 0; r < 4; ++r) sv.h2[r] = pk2bf(acc[2*r], acc[2*r+1]);
            *(short8*)(vcatT + ((size_t)h * 64 + c) * N_ + i0) = sv.v;
        }
    } else {
        if (t < 72) Rsh[t / 9][t % 9] = pose_r[(i0 + t / 9) * 9 + t % 9];
        else if (t < 96) {
            int r = (t - 72) / 3, c = (t - 72) % 3;
            Tsh[r][c] = pose_t[(i0 + r) * 3 + c];
        }

        if (t < 288) {
            const float* __restrict__ w;
            int col, ldw;
            if (seg == 3) {
                if (t < 144) { w = w_pq; col = t;       ldw = 144; }
                else         { w = w_pk; col = t - 144; ldw = 144; }
            } else         { w = w_pv; col = t;       ldw = 288; }
            float acc[8];
            #pragma unroll
            for (int r = 0; r < 8; ++r) acc[r] = 0.f;
            for (int d = 0; d < D_; d += 4) {
                float4 xr[8];
                #pragma unroll
                for (int r = 0; r < 8; ++r)
                    xr[r] = *(const float4*)(x1d + (i0 + r) * D_ + d);
                #pragma unroll
                for (int e = 0; e < 4; ++e) {
                    float wv = w[(d + e) * ldw + col];
                    #pragma unroll
                    for (int r = 0; r < 8; ++r)
                        acc[r] += ((const float*)&xr[r])[e] * wv;
                }
            }
            #pragma unroll
            for (int r = 0; r < 8; ++r) raw[r][t] = acc[r];
        }
        __syncthreads();

        if (t < 288) {
            const int x3   = t % 3;
            const int base = t - x3;
            if (seg == 3) {
                const int c = (t < 144) ? t : t - 144;
                if (t < 144) {
                    #pragma unroll
                    for (int r = 0; r < 8; ++r) {
                        float g = Rsh[r][0 + x3] * raw[r][base]
                                + Rsh[r][3 + x3] * raw[r][base + 1]
                                + Rsh[r][6 + x3] * raw[r][base + 2] + Tsh[r][x3];
                        qp[(i0 + r) * 144 + c] = g;
                    }
                } else {
                    float g[8];
                    #pragma unroll
                    for (int r = 0; r < 8; ++r)
                        g[r] = Rsh[r][0 + x3] * raw[r][base]
                             + Rsh[r][3 + x3] * raw[r][base + 1]
                             + Rsh[r][6 + x3] * raw[r][base + 2] + Tsh[r][x3];
                    *(float4*)(kpt + c * N_ + i0)     = make_float4(g[0], g[1], g[2], g[3]);
                    *(float4*)(kpt + c * N_ + i0 + 4) = make_float4(g[4], g[5], g[6], g[7]);
                }
            } else {
                int h = t / 24, pc = t % 24;
                float g[8];
                #pragma unroll
                for (int r = 0; r < 8; ++r)
                    g[r] = Rsh[r][0 + x3] * raw[r][base]
                         + Rsh[r][3 + x3] * raw[r][base + 1]
                         + Rsh[r][6 + x3] * raw[r][base + 2] + Tsh[r][x3];
                s8u sv;
                #pragma unroll
                for (int r = 0; r < 4; ++r) sv.h2[r] = pk2bf(g[2*r], g[2*r+1]);
                *(short8*)(vcatT + ((size_t)h * 64 + 32 + pc) * N_ + i0) = sv.v;
            }
        }
    }
}

// ---------------------------------------------------------------------------
// K2 (k_big): one block per i (512 blocks x 512 thr). Single pass over x2d.
// P3's head loop is schedule-pinned (sched_barrier(0) per iteration) so the
// 12x(32+12) global loads cannot be hoisted into one giant live set (the
// round-5 spill: 4KB/thread scratch -> 1.7GB HBM traffic).
// ---------------------------------------------------------------------------
__global__ __launch_bounds__(512) void k_big(
    const float* __restrict__ x2d, const float* __restrict__ w_pb,
    const float* __restrict__ qs, const float* __restrict__ kst,
    const float* __restrict__ qp, const float* __restrict__ kpt,
    const float* __restrict__ bias, const float* __restrict__ tpw,
    unsigned short* __restrict__ attn_bf, float* __restrict__ tmp)
{
    __shared__ unsigned char smem[158528];
    char*  x2b  = (char*)smem;                       // bf16 [512][128], swizzled
    float* vbuf = (float*)(smem + 131072);           // fp32 [12][512] pair logits
    unsigned int* abufw = (unsigned int*)vbuf;       // alias: [512][6] 2xbf16 attn
    float* red  = vbuf + 3072;                       // fp32 [1536] tmp reduce
    float* qsh  = (float*)(smem + 131072 + 24576);   // [384]
    float* qph  = qsh + 384;                         // [144]
    float* wredm = qph + 144;                        // [8][12]
    float* wreds = wredm + 96;                       // [8][12]

    const int i    = blockIdx.x;
    const int t    = threadIdx.x;
    const int lane = t & 63;
    const int wid  = t >> 6;        // 0..7
    const int quad = lane >> 4;
    const int col  = lane & 15;

    // ---- P0: stage q rows + x2d[i] -> swizzled bf16 LDS ----
    if (t < 384) qsh[t] = qs[i * D_ + t];
    if (t < 144) qph[t] = qp[i * 144 + t];
    {
        const float* xb = x2d + (size_t)i * N_ * P_;
        const int jl = t >> 5, p4 = t & 31;
        #pragma unroll 4
        for (int q2 = 0; q2 < 32; ++q2) {
            int j = q2 * 16 + jl;
            float4 f = *(const float4*)(xb + j * P_ + p4 * 4);
            s4u sv; sv.h2[0] = pk2bf(f.x, f.y); sv.h2[1] = pk2bf(f.z, f.w);
            int byte = (j * 256 + p4 * 8) ^ ((j & 7) << 4);
            *(unsigned long long*)(x2b + byte) = sv.u;
        }
    }
    __syncthreads();   // B1

    // ---- P2: pair logits MFMA ----
    {
        const float pair_w = 0.57735027f;
        short8 bfr[4];
        #pragma unroll
        for (int kt = 0; kt < 4; ++kt) {
            #pragma unroll
            for (int jj = 0; jj < 8; ++jj) {
                int p = kt * 32 + quad * 8 + jj;
                bfr[kt][jj] = (col < 12) ? (short)f2bf(w_pb[p * 12 + col]) : (short)0;
            }
        }
        #pragma unroll
        for (int s = 0; s < 4; ++s) {
            const int jt   = wid * 4 + s;
            const int jrow = jt * 16 + col;
            f32x4 acc = {0.f, 0.f, 0.f, 0.f};
            #pragma unroll
            for (int kt = 0; kt < 4; ++kt) {
                int addr = (jrow * 256 + (kt * 32 + quad * 8) * 2) ^ ((jrow & 7) << 4);
                short8 a = *(const short8*)(x2b + addr);
                acc = __builtin_amdgcn_mfma_f32_16x16x32_bf16(a, bfr[kt], acc, 0, 0, 0);
            }
            if (col < 12) {
                #pragma unroll
                for (int r = 0; r < 4; ++r)
                    vbuf[col * N_ + jt * 16 + quad * 4 + r] = pair_w * acc[r];
            }
        }
    }
    __syncthreads();   // B2

    // ---- P3: full logits + softmax (thread j = t) ----
    {
        const int j = t;
        const float scalar_w = 0.10206207f;
        float v[12];
        #pragma unroll
        for (int h = 0; h < 12; ++h) {
            float kv[32];
            #pragma unroll
            for (int c = 0; c < 32; ++c) kv[c] = kst[(h * 32 + c) * N_ + j];
            float kp[12];
            #pragma unroll
            for (int c = 0; c < 12; ++c) kp[c] = kpt[(h * 12 + c) * N_ + j];
            float s = 0.f;
            #pragma unroll
            for (int c = 0; c < 32; ++c) s += qsh[h * 32 + c] * kv[c];
            float dsum = 0.f;
            #pragma unroll
            for (int p = 0; p < 4; ++p) {
                float dx = qph[h * 12 + p * 3 + 0] - kp[p * 3 + 0];
                float dy = qph[h * 12 + p * 3 + 1] - kp[p * 3 + 1];
                float dz = qph[h * 12 + p * 3 + 2] - kp[p * 3 + 2];
                dsum += sqrtf(dx * dx + dy * dy + dz * dz);
            }
            float pwh = 0.13608276f * log1pf(expf(tpw[h]));
            v[h] = scalar_w * s - 0.5f * pwh * dsum
                 + bias[i * N_ + j] + vbuf[h * N_ + j];
            // pin schedule: forbid hoisting head h+1's 44 loads above this
            // point (round-5's 4KB/thread scratch spill came from that hoist)
            __builtin_amdgcn_sched_barrier(0);
        }

        // wave max per h
        #pragma unroll
        for (int h = 0; h < 12; ++h) {
            float mt = v[h];
            #pragma unroll
            for (int off = 1; off < 64; off <<= 1)
                mt = fmaxf(mt, __shfl_xor(mt, off));
            if (lane == 0) wredm[wid * 12 + h] = mt;
        }
        __syncthreads();   // B3 (all vbuf reads done before this)

        float m[12];
        #pragma unroll
        for (int h = 0; h < 12; ++h) {
            float mm = wredm[h];
            #pragma unroll
            for (int w = 1; w < 8; ++w) mm = fmaxf(mm, wredm[w * 12 + h]);
            m[h] = mm;
        }
        float e[12];
        #pragma unroll
        for (int h = 0; h < 12; ++h) {
            e[h] = __expf(v[h] - m[h]);
            float s2 = e[h];
            #pragma unroll
            for (int off = 1; off < 64; off <<= 1)
                s2 += __shfl_xor(s2, off);
            if (lane == 0) wreds[wid * 12 + h] = s2;
        }
        // zero tmp-reduce buffer (safe: vbuf reads completed before B3)
        for (int idx = t; idx < 1536; idx += 512) red[idx] = 0.f;
        __syncthreads();   // B4

        float a[12];
        #pragma unroll
        for (int h = 0; h < 12; ++h) {
            float ss = wreds[h];
            #pragma unroll
            for (int w = 1; w < 8; ++w) ss += wreds[w * 12 + h];
            a[h] = e[h] * (1.0f / ss);
        }
        #pragma unroll
        for (int k = 0; k < 6; ++k) {
            short2 pk = pk2bf(a[2 * k], a[2 * k + 1]);
            abufw[j * 6 + k] = *(unsigned int*)&pk;
        }
        #pragma unroll
        for (int h = 0; h < 12; ++h)
            attn_bf[((size_t)(h * N_ + i)) * N_ + j] = f2bf(a[h]);
    }
    __syncthreads();   // B5

    // ---- P4: tmp[i] = attn @ x2d (from LDS bf16) ----
    {
        const int p2 = (lane) * 2;          // 0..126 even (64 lanes x 2p = 128)
        float acc[12][2];
        #pragma unroll
        for (int h = 0; h < 12; ++h) { acc[h][0] = 0.f; acc[h][1] = 0.f; }
        for (int jj = 0; jj < 64; ++jj) {
            int j = wid * 64 + jj;
            int byte = (j * 256 + p2 * 2) ^ ((j & 7) << 4);
            unsigned int xw = *(const unsigned int*)(x2b + byte);
            float x0 = bf2f((unsigned short)(xw & 0xffff));
            float x1 = bf2f((unsigned short)(xw >> 16));
            #pragma unroll
            for (int k = 0; k < 6; ++k) {
                unsigned int aw = abufw[j * 6 + k];          // broadcast
                float a0 = bf2f((unsigned short)(aw & 0xffff));
                float a1 = bf2f((unsigned short)(aw >> 16));
                acc[2 * k][0]     += a0 * x0; acc[2 * k][1]     += a0 * x1;
                acc[2 * k + 1][0] += a1 * x0; acc[2 * k + 1][1] += a1 * x1;
            }
        }
        #pragma unroll
        for (int h = 0; h < 12; ++h) {
            atomicAdd(&red[h * 128 + p2],     acc[h][0]);
            atomicAdd(&red[h * 128 + p2 + 1], acc[h][1]);
        }
    }
    __syncthreads();   // B6
    for (int idx = t; idx < 1536; idx += 512)
        tmp[(size_t)i * 1536 + idx] = red[idx];
}

// ---------------------------------------------------------------------------
// K3 (k_aggr): attn_bf @ vcatT via MFMA (384 blocks x 256 thr)
// ---------------------------------------------------------------------------
__global__ __launch_bounds__(256) void k_aggr(
    const unsigned short* __restrict__ attn_bf,
    const unsigned short* __restrict__ vcatT,
    float* __restrict__ feat, float* __restrict__ outpg)
{
    const int t    = threadIdx.x;
    const int bid  = blockIdx.x;
    const int h    = bid >> 5;
    const int i0   = (bid & 31) << 4;
    const int wid  = t >> 6;
    const int lane = t & 63;
    const int quad = lane >> 4;
    const int col  = lane & 15;
    const int c    = wid * 16 + col;
    const bool cvalid = (c < 56);

    const unsigned short* arow = attn_bf + ((size_t)(h * N_ + i0 + col)) * N_;
    const unsigned short* brow = vcatT + ((size_t)h * 64 + c) * N_;

    f32x4 acc = {0.f, 0.f, 0.f, 0.f};
    #pragma unroll
    for (int kt = 0; kt < 16; ++kt) {
        const int k0 = kt * 32 + quad * 8;
        short8 a = *(const short8*)(arow + k0);
        short8 b;
        if (cvalid) b = *(const short8*)(brow + k0);
        else { b[0]=0;b[1]=0;b[2]=0;b[3]=0;b[4]=0;b[5]=0;b[6]=0;b[7]=0; }
        acc = __builtin_amdgcn_mfma_f32_16x16x32_bf16(a, b, acc, 0, 0, 0);
    }
    #pragma unroll
    for (int r = 0; r < 4; ++r) {
        int i = i0 + quad * 4 + r;
        if (c < 32)       feat[(size_t)i * 1152 + h * 32 + c] = acc[r];
        else if (c < 56)  outpg[((size_t)i * 12 + h) * 24 + (c - 32)] = acc[r];
    }
}

__global__ __launch_bounds__(384) void k_feat(
    const float* __restrict__ tmp, const float* __restrict__ outpg,
    const float* __restrict__ pose_t, const float* __restrict__ pose_r,
    const float* __restrict__ w_pairv, float* __restrict__ feat)
{
    const int i = blockIdx.x;
    const int t = threadIdx.x;
    __shared__ float tsh[1536];
    __shared__ float pg[288];
    __shared__ float pl[288];
    __shared__ float Rsh[9], Tsh[3];

    for (int idx = t; idx < 1536; idx += 384) tsh[idx] = tmp[(size_t)i * 1536 + idx];
    if (t < 288) pg[t] = outpg[i * 288 + t];
    if (t < 9) Rsh[t] = pose_r[i * 9 + t];
    if (t < 3) Tsh[t] = pose_t[i * 3 + t];
    __syncthreads();

    {
        int h = t >> 5;
        const float* ts = tsh + h * 128;
        float acc = 0.f;
        #pragma unroll 4
        for (int p = 0; p < 128; ++p) acc += ts[p] * w_pairv[p * D_ + t];
        feat[(size_t)i * 1152 + 672 + t] = acc;
    }
    if (t < 288) {
        int x3 = t % 3, base = t - x3;
        float g0 = pg[base + 0] - Tsh[0];
        float g1 = pg[base + 1] - Tsh[1];
        float g2 = pg[base + 2] - Tsh[2];
        float v = Rsh[x3*3+0]*g0 + Rsh[x3*3+1]*g1 + Rsh[x3*3+2]*g2;
        pl[t] = v;
        feat[(size_t)i * 1152 + 384 + t] = v;
    }
    __syncthreads();
    if (t < 96) {
        float a = pl[t*3], b = pl[t*3+1], c = pl[t*3+2];
        feat[(size_t)i * 1152 + 1056 + t] = sqrtf(a*a + b*b + c*c);
    }
}

__global__ __launch_bounds__(384) void k_out_part(
    const float* __restrict__ feat, const float* __restrict__ w_out,
    float* __restrict__ part)
{
    const int kc = blockIdx.x >> 6;
    const int i0 = (blockIdx.x & 63) * 8;
    const int t  = threadIdx.x;
    const int k0 = kc * 144;

    float acc[8];
    #pragma unroll
    for (int r = 0; r < 8; ++r) acc[r] = 0.f;

    for (int d = 0; d < 144; d += 4) {
        float4 fr[8];
        #pragma unroll
        for (int r = 0; r < 8; ++r)
            fr[r] = *(const float4*)(feat + (size_t)(i0 + r) * 1152 + k0 + d);
        #pragma unroll
        for (int e = 0; e < 4; ++e) {
            float wv = w_out[(size_t)(k0 + d + e) * D_ + t];
            #pragma unroll
            for (int r = 0; r < 8; ++r)
                acc[r] += ((const float*)&fr[r])[e] * wv;
        }
    }
    #pragma unroll
    for (int r = 0; r < 8; ++r)
        part[((size_t)kc * N_ + i0 + r) * D_ + t] = acc[r];
}

__global__ __launch_bounds__(256) void k_out_red(
    const float* __restrict__ part, const float* __restrict__ b_out,
    float* __restrict__ out)
{
    const int idx = blockIdx.x * 256 + threadIdx.x;
    float s = b_out[idx % D_];
    #pragma unroll
    for (int kc = 0; kc < 8; ++kc) s += part[(size_t)kc * (N_ * D_) + idx];
    out[idx] = s;
}

extern "C" void kernel_launch(void* const* d_in, const int* in_sizes, int n_in,
                              void* d_out, int out_size, void* d_ws, size_t ws_size,
                              hipStream_t stream)
{
    (void)in_sizes; (void)n_in; (void)out_size; (void)ws_size;
    const float* x1d     = (const float*)d_in[0];
    const float* x2d     = (const float*)d_in[1];
    const float* pose_t  = (const float*)d_in[2];
    const float* pose_r  = (const float*)d_in[3];
    const float* bias    = (const float*)d_in[4];
    const float* w_sq    = (const float*)d_in[5];
    const float* w_sk    = (const float*)d_in[6];
    const float* w_sv    = (const float*)d_in[7];
    const float* w_pb    = (const float*)d_in[8];
    const float* w_pq    = (const float*)d_in[9];
    const float* w_pk    = (const float*)d_in[10];
    const float* w_pv    = (const float*)d_in[11];
    const float* tpw     = (const float*)d_in[12];
    const float* w_pairv = (const float*)d_in[13];
    const float* w_out   = (const float*)d_in[14];
    const float* b_out   = (const float*)d_in[15];
    float* out = (float*)d_out;

    float* ws = (float*)d_ws;
    float* qs      = ws;
    float* kst     = qs      + 196608;
    float* qp      = kst     + 196608;
    float* kpt     = qp      + 73728;
    float* pairlog = kpt     + 73728;    // unused now (kept for layout stability)
    float* tmp     = pairlog + 3145728;
    float* outpg   = tmp     + 786432;
    float* feat    = outpg   + 147456;
    float* part    = feat    + 589824;   // 1572864 floats
    unsigned short* attn_bf = (unsigned short*)(part + 1572864);  // 12*512*512
    unsigned short* vcatT   = attn_bf + (size_t)12 * N_ * N_;     // 12*64*512

    hipLaunchKernelGGL(k_front, dim3(320), dim3(384), 0, stream,
                       x1d, pose_t, pose_r, w_sq, w_sk, w_sv, w_pq, w_pk, w_pv,
                       qs, kst, qp, kpt, vcatT);
    hipLaunchKernelGGL(k_big, dim3(N_), dim3(512), 0, stream,
                       x2d, w_pb, qs, kst, qp, kpt, bias, tpw, attn_bf, tmp);
    hipLaunchKernelGGL(k_aggr, dim3(384), dim3(256), 0, stream,
                       attn_bf, vcatT, feat, outpg);
    hipLaunchKernelGGL(k_feat, dim3(N_), dim3(384), 0, stream,
                       tmp, outpg, pose_t, pose_r, w_pairv, feat);
    hipLaunchKernelGGL(k_out_part, dim3(512), dim3(384), 0, stream,
                       feat, w_out, part);
    hipLaunchKernelGGL(k_out_red, dim3(768), dim3(256), 0, stream,
                       part, b_out, out);
}

// Round 8
// 1154.325 us; speedup vs baseline: 1.1817x; 1.0030x over previous
//
#include <hip/hip_runtime.h>
#include <hip/hip_bf16.h>
#include <math.h>

#define N_  512
#define D_  384
#define H_  12
#define DK_ 32
#define P_  128

typedef short short8 __attribute__((ext_vector_type(8)));
typedef float f32x4  __attribute__((ext_vector_type(4)));

static __device__ __forceinline__ unsigned short f2bf(float f) {
    union { float f; unsigned int u; } v; v.f = f;
    unsigned int r = (v.u + 0x7FFFu + ((v.u >> 16) & 1u)) >> 16;  // RNE
    return (unsigned short)r;
}
static __device__ __forceinline__ float bf2f(unsigned short u) {
    union { unsigned int u; float f; } v; v.u = ((unsigned int)u) << 16;
    return v.f;
}
static __device__ __forceinline__ short2 pk2bf(float a, float b) {
    __hip_bfloat162 h = __float22bfloat162_rn(make_float2(a, b));
    return *(short2*)&h;
}
typedef union { short8 v; short2 h2[4]; } s8u;
typedef union { short2 h2[2]; unsigned long long u; } s4u;

// ---------------------------------------------------------------------------
// K1: projections + affine ONLY (320 blocks x 384 thr)
// ---------------------------------------------------------------------------
__global__ __launch_bounds__(384) void k_front(
    const float* __restrict__ x1d, const float* __restrict__ pose_t,
    const float* __restrict__ pose_r,
    const float* __restrict__ w_sq, const float* __restrict__ w_sk,
    const float* __restrict__ w_sv, const float* __restrict__ w_pq,
    const float* __restrict__ w_pk, const float* __restrict__ w_pv,
    float* __restrict__ qs, float* __restrict__ kst,
    float* __restrict__ qp, float* __restrict__ kpt,
    unsigned short* __restrict__ vcatT)
{
    __shared__ float raw[8][288];
    __shared__ float Rsh[8][9];
    __shared__ float Tsh[8][3];

    const int t   = threadIdx.x;
    const int b   = blockIdx.x;
    const int seg = b >> 6;            // 0..4
    const int i0  = (b & 63) * 8;

    if (seg < 3) {
        const float* __restrict__ w = (seg == 0) ? w_sq : (seg == 1) ? w_sk : w_sv;
        float acc[8];
        #pragma unroll
        for (int r = 0; r < 8; ++r) acc[r] = 0.f;
        for (int d = 0; d < D_; d += 4) {
            float4 xr[8];
            #pragma unroll
            for (int r = 0; r < 8; ++r)
                xr[r] = *(const float4*)(x1d + (i0 + r) * D_ + d);
            #pragma unroll
            for (int e = 0; e < 4; ++e) {
                float wv = w[(d + e) * D_ + t];
                #pragma unroll
                for (int r = 0; r < 8; ++r)
                    acc[r] += ((const float*)&xr[r])[e] * wv;
            }
        }
        if (seg == 0) {
            #pragma unroll
            for (int r = 0; r < 8; ++r) qs[(i0 + r) * D_ + t] = acc[r];
        } else if (seg == 1) {
            *(float4*)(kst + t * N_ + i0)     = make_float4(acc[0], acc[1], acc[2], acc[3]);
            *(float4*)(kst + t * N_ + i0 + 4) = make_float4(acc[4], acc[5], acc[6], acc[7]);
        } else {
            int h = t >> 5, c = t & 31;
            s8u sv;
            #pragma unroll
            for (int r = 0; r < 4; ++r) sv.h2[r] = pk2bf(acc[2*r], acc[2*r+1]);
            *(short8*)(vcatT + ((size_t)h * 64 + c) * N_ + i0) = sv.v;
        }
    } else {
        if (t < 72) Rsh[t / 9][t % 9] = pose_r[(i0 + t / 9) * 9 + t % 9];
        else if (t < 96) {
            int r = (t - 72) / 3, c = (t - 72) % 3;
            Tsh[r][c] = pose_t[(i0 + r) * 3 + c];
        }

        if (t < 288) {
            const float* __restrict__ w;
            int col, ldw;
            if (seg == 3) {
                if (t < 144) { w = w_pq; col = t;       ldw = 144; }
                else         { w = w_pk; col = t - 144; ldw = 144; }
            } else         { w = w_pv; col = t;       ldw = 288; }
            float acc[8];
            #pragma unroll
            for (int r = 0; r < 8; ++r) acc[r] = 0.f;
            for (int d = 0; d < D_; d += 4) {
                float4 xr[8];
                #pragma unroll
                for (int r = 0; r < 8; ++r)
                    xr[r] = *(const float4*)(x1d + (i0 + r) * D_ + d);
                #pragma unroll
                for (int e = 0; e < 4; ++e) {
                    float wv = w[(d + e) * ldw + col];
                    #pragma unroll
                    for (int r = 0; r < 8; ++r)
                        acc[r] += ((const float*)&xr[r])[e] * wv;
                }
            }
            #pragma unroll
            for (int r = 0; r < 8; ++r) raw[r][t] = acc[r];
        }
        __syncthreads();

        if (t < 288) {
            const int x3   = t % 3;
            const int base = t - x3;
            if (seg == 3) {
                const int c = (t < 144) ? t : t - 144;
                if (t < 144) {
                    #pragma unroll
                    for (int r = 0; r < 8; ++r) {
                        float g = Rsh[r][0 + x3] * raw[r][base]
                                + Rsh[r][3 + x3] * raw[r][base + 1]
                                + Rsh[r][6 + x3] * raw[r][base + 2] + Tsh[r][x3];
                        qp[(i0 + r) * 144 + c] = g;
                    }
                } else {
                    float g[8];
                    #pragma unroll
                    for (int r = 0; r < 8; ++r)
                        g[r] = Rsh[r][0 + x3] * raw[r][base]
                             + Rsh[r][3 + x3] * raw[r][base + 1]
                             + Rsh[r][6 + x3] * raw[r][base + 2] + Tsh[r][x3];
                    *(float4*)(kpt + c * N_ + i0)     = make_float4(g[0], g[1], g[2], g[3]);
                    *(float4*)(kpt + c * N_ + i0 + 4) = make_float4(g[4], g[5], g[6], g[7]);
                }
            } else {
                int h = t / 24, pc = t % 24;
                float g[8];
                #pragma unroll
                for (int r = 0; r < 8; ++r)
                    g[r] = Rsh[r][0 + x3] * raw[r][base]
                         + Rsh[r][3 + x3] * raw[r][base + 1]
                         + Rsh[r][6 + x3] * raw[r][base + 2] + Tsh[r][x3];
                s8u sv;
                #pragma unroll
                for (int r = 0; r < 4; ++r) sv.h2[r] = pk2bf(g[2*r], g[2*r+1]);
                *(short8*)(vcatT + ((size_t)h * 64 + 32 + pc) * N_ + i0) = sv.v;
            }
        }
    }
}

// ---------------------------------------------------------------------------
// K2 (k_big): one block per i (512 blocks x 512 thr). Single pass over x2d.
// __launch_bounds__(512, 2): LDS (158KB) pins us at 1 WG/CU = 2 waves/EU
// anyway, so let the allocator use 256 VGPRs. Round 6's default cap (128)
// spilled ~3KB/thread -> 1.2GB phantom HBM traffic. sched_barrier in P3
// retained to bound the hoisted-load live set.
// ---------------------------------------------------------------------------
__global__ __launch_bounds__(512, 2) void k_big(
    const float* __restrict__ x2d, const float* __restrict__ w_pb,
    const float* __restrict__ qs, const float* __restrict__ kst,
    const float* __restrict__ qp, const float* __restrict__ kpt,
    const float* __restrict__ bias, const float* __restrict__ tpw,
    unsigned short* __restrict__ attn_bf, float* __restrict__ tmp)
{
    __shared__ unsigned char smem[158528];
    char*  x2b  = (char*)smem;                       // bf16 [512][128], swizzled
    float* vbuf = (float*)(smem + 131072);           // fp32 [12][512] pair logits
    unsigned int* abufw = (unsigned int*)vbuf;       // alias: [512][6] 2xbf16 attn
    float* red  = vbuf + 3072;                       // fp32 [1536] tmp reduce
    float* qsh  = (float*)(smem + 131072 + 24576);   // [384]
    float* qph  = qsh + 384;                         // [144]
    float* wredm = qph + 144;                        // [8][12]
    float* wreds = wredm + 96;                       // [8][12]

    const int i    = blockIdx.x;
    const int t    = threadIdx.x;
    const int lane = t & 63;
    const int wid  = t >> 6;        // 0..7
    const int quad = lane >> 4;
    const int col  = lane & 15;

    // ---- P0: stage q rows + x2d[i] -> swizzled bf16 LDS ----
    if (t < 384) qsh[t] = qs[i * D_ + t];
    if (t < 144) qph[t] = qp[i * 144 + t];
    {
        const float* xb = x2d + (size_t)i * N_ * P_;
        const int jl = t >> 5, p4 = t & 31;
        #pragma unroll 4
        for (int q2 = 0; q2 < 32; ++q2) {
            int j = q2 * 16 + jl;
            float4 f = *(const float4*)(xb + j * P_ + p4 * 4);
            s4u sv; sv.h2[0] = pk2bf(f.x, f.y); sv.h2[1] = pk2bf(f.z, f.w);
            int byte = (j * 256 + p4 * 8) ^ ((j & 7) << 4);
            *(unsigned long long*)(x2b + byte) = sv.u;
        }
    }
    __syncthreads();   // B1

    // ---- P2: pair logits MFMA ----
    {
        const float pair_w = 0.57735027f;
        short8 bfr[4];
        #pragma unroll
        for (int kt = 0; kt < 4; ++kt) {
            #pragma unroll
            for (int jj = 0; jj < 8; ++jj) {
                int p = kt * 32 + quad * 8 + jj;
                bfr[kt][jj] = (col < 12) ? (short)f2bf(w_pb[p * 12 + col]) : (short)0;
            }
        }
        #pragma unroll
        for (int s = 0; s < 4; ++s) {
            const int jt   = wid * 4 + s;
            const int jrow = jt * 16 + col;
            f32x4 acc = {0.f, 0.f, 0.f, 0.f};
            #pragma unroll
            for (int kt = 0; kt < 4; ++kt) {
                int addr = (jrow * 256 + (kt * 32 + quad * 8) * 2) ^ ((jrow & 7) << 4);
                short8 a = *(const short8*)(x2b + addr);
                acc = __builtin_amdgcn_mfma_f32_16x16x32_bf16(a, bfr[kt], acc, 0, 0, 0);
            }
            if (col < 12) {
                #pragma unroll
                for (int r = 0; r < 4; ++r)
                    vbuf[col * N_ + jt * 16 + quad * 4 + r] = pair_w * acc[r];
            }
        }
    }
    __syncthreads();   // B2

    // ---- P3: full logits + softmax (thread j = t) ----
    {
        const int j = t;
        const float scalar_w = 0.10206207f;
        float v[12];
        #pragma unroll
        for (int h = 0; h < 12; ++h) {
            float kv[32];
            #pragma unroll
            for (int c = 0; c < 32; ++c) kv[c] = kst[(h * 32 + c) * N_ + j];
            float kp[12];
            #pragma unroll
            for (int c = 0; c < 12; ++c) kp[c] = kpt[(h * 12 + c) * N_ + j];
            float s = 0.f;
            #pragma unroll
            for (int c = 0; c < 32; ++c) s += qsh[h * 32 + c] * kv[c];
            float dsum = 0.f;
            #pragma unroll
            for (int p = 0; p < 4; ++p) {
                float dx = qph[h * 12 + p * 3 + 0] - kp[p * 3 + 0];
                float dy = qph[h * 12 + p * 3 + 1] - kp[p * 3 + 1];
                float dz = qph[h * 12 + p * 3 + 2] - kp[p * 3 + 2];
                dsum += sqrtf(dx * dx + dy * dy + dz * dz);
            }
            float pwh = 0.13608276f * log1pf(expf(tpw[h]));
            v[h] = scalar_w * s - 0.5f * pwh * dsum
                 + bias[i * N_ + j] + vbuf[h * N_ + j];
            // pin schedule: forbid hoisting head h+1's 44 loads above this
            // point (bounds the live set; with 256 VGPRs this now fits)
            __builtin_amdgcn_sched_barrier(0);
        }

        // wave max per h
        #pragma unroll
        for (int h = 0; h < 12; ++h) {
            float mt = v[h];
            #pragma unroll
            for (int off = 1; off < 64; off <<= 1)
                mt = fmaxf(mt, __shfl_xor(mt, off));
            if (lane == 0) wredm[wid * 12 + h] = mt;
        }
        __syncthreads();   // B3 (all vbuf reads done before this)

        float m[12];
        #pragma unroll
        for (int h = 0; h < 12; ++h) {
            float mm = wredm[h];
            #pragma unroll
            for (int w = 1; w < 8; ++w) mm = fmaxf(mm, wredm[w * 12 + h]);
            m[h] = mm;
        }
        float e[12];
        #pragma unroll
        for (int h = 0; h < 12; ++h) {
            e[h] = __expf(v[h] - m[h]);
            float s2 = e[h];
            #pragma unroll
            for (int off = 1; off < 64; off <<= 1)
                s2 += __shfl_xor(s2, off);
            if (lane == 0) wreds[wid * 12 + h] = s2;
        }
        // zero tmp-reduce buffer (safe: vbuf reads completed before B3)
        for (int idx = t; idx < 1536; idx += 512) red[idx] = 0.f;
        __syncthreads();   // B4

        float a[12];
        #pragma unroll
        for (int h = 0; h < 12; ++h) {
            float ss = wreds[h];
            #pragma unroll
            for (int w = 1; w < 8; ++w) ss += wreds[w * 12 + h];
            a[h] = e[h] * (1.0f / ss);
        }
        #pragma unroll
        for (int k = 0; k < 6; ++k) {
            short2 pk = pk2bf(a[2 * k], a[2 * k + 1]);
            abufw[j * 6 + k] = *(unsigned int*)&pk;
        }
        #pragma unroll
        for (int h = 0; h < 12; ++h)
            attn_bf[((size_t)(h * N_ + i)) * N_ + j] = f2bf(a[h]);
    }
    __syncthreads();   // B5

    // ---- P4: tmp[i] = attn @ x2d (from LDS bf16) ----
    {
        const int p2 = (lane) * 2;          // 0..126 even (64 lanes x 2p = 128)
        float acc[12][2];
        #pragma unroll
        for (int h = 0; h < 12; ++h) { acc[h][0] = 0.f; acc[h][1] = 0.f; }
        for (int jj = 0; jj < 64; ++jj) {
            int j = wid * 64 + jj;
            int byte = (j * 256 + p2 * 2) ^ ((j & 7) << 4);
            unsigned int xw = *(const unsigned int*)(x2b + byte);
            float x0 = bf2f((unsigned short)(xw & 0xffff));
            float x1 = bf2f((unsigned short)(xw >> 16));
            #pragma unroll
            for (int k = 0; k < 6; ++k) {
                unsigned int aw = abufw[j * 6 + k];          // broadcast
                float a0 = bf2f((unsigned short)(aw & 0xffff));
                float a1 = bf2f((unsigned short)(aw >> 16));
                acc[2 * k][0]     += a0 * x0; acc[2 * k][1]     += a0 * x1;
                acc[2 * k + 1][0] += a1 * x0; acc[2 * k + 1][1] += a1 * x1;
            }
        }
        #pragma unroll
        for (int h = 0; h < 12; ++h) {
            atomicAdd(&red[h * 128 + p2],     acc[h][0]);
            atomicAdd(&red[h * 128 + p2 + 1], acc[h][1]);
        }
    }
    __syncthreads();   // B6
    for (int idx = t; idx < 1536; idx += 512)
        tmp[(size_t)i * 1536 + idx] = red[idx];
}

// ---------------------------------------------------------------------------
// K3 (k_aggr): attn_bf @ vcatT via MFMA (384 blocks x 256 thr)
// ---------------------------------------------------------------------------
__global__ __launch_bounds__(256) void k_aggr(
    const unsigned short* __restrict__ attn_bf,
    const unsigned short* __restrict__ vcatT,
    float* __restrict__ feat, float* __restrict__ outpg)
{
    const int t    = threadIdx.x;
    const int bid  = blockIdx.x;
    const int h    = bid >> 5;
    const int i0   = (bid & 31) << 4;
    const int wid  = t >> 6;
    const int lane = t & 63;
    const int quad = lane >> 4;
    const int col  = lane & 15;
    const int c    = wid * 16 + col;
    const bool cvalid = (c < 56);

    const unsigned short* arow = attn_bf + ((size_t)(h * N_ + i0 + col)) * N_;
    const unsigned short* brow = vcatT + ((size_t)h * 64 + c) * N_;

    f32x4 acc = {0.f, 0.f, 0.f, 0.f};
    #pragma unroll
    for (int kt = 0; kt < 16; ++kt) {
        const int k0 = kt * 32 + quad * 8;
        short8 a = *(const short8*)(arow + k0);
        short8 b;
        if (cvalid) b = *(const short8*)(brow + k0);
        else { b[0]=0;b[1]=0;b[2]=0;b[3]=0;b[4]=0;b[5]=0;b[6]=0;b[7]=0; }
        acc = __builtin_amdgcn_mfma_f32_16x16x32_bf16(a, b, acc, 0, 0, 0);
    }
    #pragma unroll
    for (int r = 0; r < 4; ++r) {
        int i = i0 + quad * 4 + r;
        if (c < 32)       feat[(size_t)i * 1152 + h * 32 + c] = acc[r];
        else if (c < 56)  outpg[((size_t)i * 12 + h) * 24 + (c - 32)] = acc[r];
    }
}

__global__ __launch_bounds__(384) void k_feat(
    const float* __restrict__ tmp, const float* __restrict__ outpg,
    const float* __restrict__ pose_t, const float* __restrict__ pose_r,
    const float* __restrict__ w_pairv, float* __restrict__ feat)
{
    const int i = blockIdx.x;
    const int t = threadIdx.x;
    __shared__ float tsh[1536];
    __shared__ float pg[288];
    __shared__ float pl[288];
    __shared__ float Rsh[9], Tsh[3];

    for (int idx = t; idx < 1536; idx += 384) tsh[idx] = tmp[(size_t)i * 1536 + idx];
    if (t < 288) pg[t] = outpg[i * 288 + t];
    if (t < 9) Rsh[t] = pose_r[i * 9 + t];
    if (t < 3) Tsh[t] = pose_t[i * 3 + t];
    __syncthreads();

    {
        int h = t >> 5;
        const float* ts = tsh + h * 128;
        float acc = 0.f;
        #pragma unroll 4
        for (int p = 0; p < 128; ++p) acc += ts[p] * w_pairv[p * D_ + t];
        feat[(size_t)i * 1152 + 672 + t] = acc;
    }
    if (t < 288) {
        int x3 = t % 3, base = t - x3;
        float g0 = pg[base + 0] - Tsh[0];
        float g1 = pg[base + 1] - Tsh[1];
        float g2 = pg[base + 2] - Tsh[2];
        float v = Rsh[x3*3+0]*g0 + Rsh[x3*3+1]*g1 + Rsh[x3*3+2]*g2;
        pl[t] = v;
        feat[(size_t)i * 1152 + 384 + t] = v;
    }
    __syncthreads();
    if (t < 96) {
        float a = pl[t*3], b = pl[t*3+1], c = pl[t*3+2];
        feat[(size_t)i * 1152 + 1056 + t] = sqrtf(a*a + b*b + c*c);
    }
}

__global__ __launch_bounds__(384) void k_out_part(
    const float* __restrict__ feat, const float* __restrict__ w_out,
    float* __restrict__ part)
{
    const int kc = blockIdx.x >> 6;
    const int i0 = (blockIdx.x & 63) * 8;
    const int t  = threadIdx.x;
    const int k0 = kc * 144;

    float acc[8];
    #pragma unroll
    for (int r = 0; r < 8; ++r) acc[r] = 0.f;

    for (int d = 0; d < 144; d += 4) {
        float4 fr[8];
        #pragma unroll
        for (int r = 0; r < 8; ++r)
            fr[r] = *(const float4*)(feat + (size_t)(i0 + r) * 1152 + k0 + d);
        #pragma unroll
        for (int e = 0; e < 4; ++e) {
            float wv = w_out[(size_t)(k0 + d + e) * D_ + t];
            #pragma unroll
            for (int r = 0; r < 8; ++r)
                acc[r] += ((const float*)&fr[r])[e] * wv;
        }
    }
    #pragma unroll
    for (int r = 0; r < 8; ++r)
        part[((size_t)kc * N_ + i0 + r) * D_ + t] = acc[r];
}

__global__ __launch_bounds__(256) void k_out_red(
    const float* __restrict__ part, const float* __restrict__ b_out,
    float* __restrict__ out)
{
    const int idx = blockIdx.x * 256 + threadIdx.x;
    float s = b_out[idx % D_];
    #pragma unroll
    for (int kc = 0; kc < 8; ++kc) s += part[(size_t)kc * (N_ * D_) + idx];
    out[idx] = s;
}

extern "C" void kernel_launch(void* const* d_in, const int* in_sizes, int n_in,
                              void* d_out, int out_size, void* d_ws, size_t ws_size,
                              hipStream_t stream)
{
    (void)in_sizes; (void)n_in; (void)out_size; (void)ws_size;
    const float* x1d     = (const float*)d_in[0];
    const float* x2d     = (const float*)d_in[1];
    const float* pose_t  = (const float*)d_in[2];
    const float* pose_r  = (const float*)d_in[3];
    const float* bias    = (const float*)d_in[4];
    const float* w_sq    = (const float*)d_in[5];
    const float* w_sk    = (const float*)d_in[6];
    const float* w_sv    = (const float*)d_in[7];
    const float* w_pb    = (const float*)d_in[8];
    const float* w_pq    = (const float*)d_in[9];
    const float* w_pk    = (const float*)d_in[10];
    const float* w_pv    = (const float*)d_in[11];
    const float* tpw     = (const float*)d_in[12];
    const float* w_pairv = (const float*)d_in[13];
    const float* w_out   = (const float*)d_in[14];
    const float* b_out   = (const float*)d_in[15];
    float* out = (float*)d_out;

    float* ws = (float*)d_ws;
    float* qs      = ws;
    float* kst     = qs      + 196608;
    float* qp      = kst     + 196608;
    float* kpt     = qp      + 73728;
    float* pairlog = kpt     + 73728;    // unused now (kept for layout stability)
    float* tmp     = pairlog + 3145728;
    float* outpg   = tmp     + 786432;
    float* feat    = outpg   + 147456;
    float* part    = feat    + 589824;   // 1572864 floats
    unsigned short* attn_bf = (unsigned short*)(part + 1572864);  // 12*512*512
    unsigned short* vcatT   = attn_bf + (size_t)12 * N_ * N_;     // 12*64*512

    hipLaunchKernelGGL(k_front, dim3(320), dim3(384), 0, stream,
                       x1d, pose_t, pose_r, w_sq, w_sk, w_sv, w_pq, w_pk, w_pv,
                       qs, kst, qp, kpt, vcatT);
    hipLaunchKernelGGL(k_big, dim3(N_), dim3(512), 0, stream,
                       x2d, w_pb, qs, kst, qp, kpt, bias, tpw, attn_bf, tmp);
    hipLaunchKernelGGL(k_aggr, dim3(384), dim3(256), 0, stream,
                       attn_bf, vcatT, feat, outpg);
    hipLaunchKernelGGL(k_feat, dim3(N_), dim3(384), 0, stream,
                       tmp, outpg, pose_t, pose_r, w_pairv, feat);
    hipLaunchKernelGGL(k_out_part, dim3(512), dim3(384), 0, stream,
                       feat, w_out, part);
    hipLaunchKernelGGL(k_out_red, dim3(768), dim3(256), 0, stream,
                       part, b_out, out);
}